// Round 2
// baseline (401.846 us; speedup 1.0000x reference)
//
#include <hip/hip_runtime.h>
#include <math.h>

#define H 128
#define TOPK 5
#define INV_TEMP 5.0f
#define ZLD 2048      // z2t column stride (>= NRES, pow2)
#define ZNODES 8      // zero-nodes per block

// ---------------- degree count ----------------
__global__ __launch_bounds__(256) void deg_kernel(
    const int* __restrict__ src, const int* __restrict__ dst,
    int* __restrict__ in_deg, int* __restrict__ out_deg, int E)
{
  int e = blockIdx.x * 256 + threadIdx.x;
  if (e < E) {
    atomicAdd(&in_deg[dst[e]], 1);
    atomicAdd(&out_deg[src[e]], 1);
  }
}

// ---------------- exclusive scan of in_deg -> offs[0..N] ----------------
__global__ __launch_bounds__(1024) void scan_kernel(
    const int* __restrict__ deg, int* __restrict__ offs, int n)
{
  __shared__ int sums[1024];
  int tid = threadIdx.x;
  int per = (n + 1023) >> 10;
  int start = tid * per;
  int end = min(start + per, n);
  int s = 0;
  for (int i = start; i < end; ++i) s += deg[i];
  sums[tid] = s;
  __syncthreads();
  for (int off = 1; off < 1024; off <<= 1) {
    int v = (tid >= off) ? sums[tid - off] : 0;
    __syncthreads();
    sums[tid] += v;
    __syncthreads();
  }
  int run = (tid == 0) ? 0 : sums[tid - 1];
  for (int i = start; i < end; ++i) { offs[i] = run; run += deg[i]; }
  if (tid == 1023) offs[n] = sums[1023];
}

// ---------------- bucket fill (payload = rel | inv<<16) ----------------
__global__ __launch_bounds__(256) void fill_kernel(
    const int* __restrict__ dst, const int* __restrict__ rel, const int* __restrict__ inv,
    const int* __restrict__ offs, int* __restrict__ cursor, int* __restrict__ bucket, int E)
{
  int e = blockIdx.x * 256 + threadIdx.x;
  if (e < E) {
    int d = dst[e];
    int pos = offs[d] + atomicAdd(&cursor[d], 1);
    bucket[pos] = rel[e] | (inv[e] << 16);
  }
}

// ---------------- zero-total-degree node list ----------------
__global__ __launch_bounds__(256) void zerolist_kernel(
    const int* __restrict__ in_deg, const int* __restrict__ out_deg,
    int* __restrict__ zlist, int* __restrict__ zcount, int N)
{
  int n = blockIdx.x * 256 + threadIdx.x;
  if (n < N && (in_deg[n] + out_deg[n]) == 0) {
    int p = atomicAdd(zcount, 1);
    zlist[p] = n;
  }
}

// ---------------- l2-normalize res_ent_emb rows -> TRANSPOSED z2t[k][j] ----------------
__global__ __launch_bounds__(64) void norm_res_kernel(
    const float* __restrict__ res, float* __restrict__ z2t, int NRES_)
{
  int r = blockIdx.x;
  int lane = threadIdx.x;
  float x0 = res[(size_t)r * H + lane];
  float x1 = res[(size_t)r * H + lane + 64];
  float ss = x0 * x0 + x1 * x1;
  #pragma unroll
  for (int off = 32; off > 0; off >>= 1) ss += __shfl_xor(ss, off, 64);
  float iv = 1.0f / fmaxf(sqrtf(ss), 1e-12f);
  z2t[(size_t)lane * ZLD + r] = x0 * iv;
  z2t[(size_t)(lane + 64) * ZLD + r] = x1 * iv;
}

// ---------------- per-node mean gather (one wave per node) ----------------
__global__ __launch_bounds__(256) void gather_kernel(
    const int* __restrict__ offs, const int* __restrict__ bucket,
    const float* __restrict__ rhead, const float* __restrict__ rtail,
    float* __restrict__ feat, int N)
{
  int gid = blockIdx.x * 256 + threadIdx.x;
  int wid = gid >> 6;
  int lane = gid & 63;
  if (wid >= N) return;
  int b = offs[wid], e2 = offs[wid + 1];
  float a0 = 0.f, a1 = 0.f;
  for (int p = b; p < e2; ++p) {
    int pay = bucket[p];
    int r = pay & 0xFFFF;
    const float* row = ((pay >> 16) ? rhead : rtail) + (size_t)r * H;
    a0 += row[lane];
    a1 += row[lane + 64];
  }
  int deg = e2 - b;
  float sc = 1.0f / (float)(deg > 0 ? deg : 1);
  feat[(size_t)wid * H + lane] = a0 * sc;
  feat[(size_t)wid * H + lane + 64] = a1 * sc;
}

// ---------------- zero-node fallback: coalesced sims GEMM + reg top-5 ----------------
// 8 zero-nodes per block. z1 rows in LDS (broadcast reads); z2t[k][j] read
// coalesced (lane = j). j-range processed in two 1024-halves so sims LDS is
// 32 KB; running per-lane top-5 carried in registers across halves.
__global__ __launch_bounds__(256) void zero_emb_kernel(
    const int* __restrict__ zlist, const int* __restrict__ zcount,
    const float* __restrict__ ent, const float* __restrict__ z2t,
    const float* __restrict__ res_raw, float* __restrict__ feat, int NRES_)
{
  __shared__ __align__(16) float z1s[ZNODES * H];      // 4 KB
  __shared__ float sims[ZNODES * 1024];                // 32 KB
  int t = threadIdx.x;
  int w = t >> 6;
  int lane = t & 63;
  int Z = *zcount;
  int ngroups = (Z + ZNODES - 1) / ZNODES;
  for (int g = blockIdx.x; g < ngroups; g += gridDim.x) {
    int zi0 = g * ZNODES;
    int nv = min(ZNODES, Z - zi0);
    // ---- normalize z1 rows: wave w handles local nodes 2w, 2w+1 ----
    #pragma unroll
    for (int c = 0; c < 2; ++c) {
      int nl = w * 2 + c;
      float x0 = 0.f, x1 = 0.f;
      if (nl < nv) {
        int n = zlist[zi0 + nl];
        x0 = ent[(size_t)n * H + lane];
        x1 = ent[(size_t)n * H + lane + 64];
        float ss = x0 * x0 + x1 * x1;
        #pragma unroll
        for (int off = 32; off > 0; off >>= 1) ss += __shfl_xor(ss, off, 64);
        float iv = 1.0f / fmaxf(sqrtf(ss), 1e-12f);
        x0 *= iv; x1 *= iv;
      }
      z1s[nl * H + lane] = x0;
      z1s[nl * H + lane + 64] = x1;
    }
    __syncthreads();

    // running top-5 (value desc, tie -> lower index), per wave-owned node
    float tv[2][TOPK]; int ti[2][TOPK];
    #pragma unroll
    for (int c = 0; c < 2; ++c)
      #pragma unroll
      for (int k = 0; k < TOPK; ++k) { tv[c][k] = -1e30f; ti[c][k] = 0x7fffffff; }

    #pragma unroll
    for (int half = 0; half < 2; ++half) {
      // ---- sims for j in [half*1024, half*1024+1024) ----
      #pragma unroll
      for (int tile = 0; tile < 2; ++tile) {
        int jl0 = tile * 512 + t;       // local j in [0,1024)
        int j0 = half * 1024 + jl0;
        int j1 = j0 + 256;
        float acc0[ZNODES], acc1[ZNODES];
        #pragma unroll
        for (int n = 0; n < ZNODES; ++n) { acc0[n] = 0.f; acc1[n] = 0.f; }
        #pragma unroll 2
        for (int k = 0; k < H; k += 4) {
          float a0[4], a1[4];
          #pragma unroll
          for (int kk = 0; kk < 4; ++kk) {
            a0[kk] = z2t[(size_t)(k + kk) * ZLD + j0];
            a1[kk] = z2t[(size_t)(k + kk) * ZLD + j1];
          }
          #pragma unroll
          for (int n = 0; n < ZNODES; ++n) {
            float4 zv = *(const float4*)&z1s[n * H + k];
            acc0[n] += zv.x * a0[0] + zv.y * a0[1] + zv.z * a0[2] + zv.w * a0[3];
            acc1[n] += zv.x * a1[0] + zv.y * a1[1] + zv.z * a1[2] + zv.w * a1[3];
          }
        }
        #pragma unroll
        for (int n = 0; n < ZNODES; ++n) {
          sims[n * 1024 + jl0] = acc0[n];
          sims[n * 1024 + jl0 + 256] = acc1[n];
        }
      }
      __syncthreads();
      // ---- update running top-5 from this half ----
      int lim = min(1024, NRES_ - half * 1024);
      #pragma unroll
      for (int c = 0; c < 2; ++c) {
        int nl = w * 2 + c;
        if (nl < nv) {
          for (int jl = lane; jl < lim; jl += 64) {
            float s = sims[nl * 1024 + jl];
            int j = half * 1024 + jl;
            if (s > tv[c][TOPK - 1] || (s == tv[c][TOPK - 1] && j < ti[c][TOPK - 1])) {
              tv[c][TOPK - 1] = s; ti[c][TOPK - 1] = j;
              #pragma unroll
              for (int k = TOPK - 1; k > 0; --k) {
                if (tv[c][k] > tv[c][k - 1] ||
                    (tv[c][k] == tv[c][k - 1] && ti[c][k] < ti[c][k - 1])) {
                  float a = tv[c][k]; tv[c][k] = tv[c][k - 1]; tv[c][k - 1] = a;
                  int bI = ti[c][k]; ti[c][k] = ti[c][k - 1]; ti[c][k - 1] = bI;
                }
              }
            }
          }
        }
      }
      __syncthreads();   // before next half overwrites sims
    }

    // ---- cross-lane merge + softmax + weighted sum ----
    #pragma unroll
    for (int c = 0; c < 2; ++c) {
      int nl = w * 2 + c;
      if (nl < nv) {
        int n = zlist[zi0 + nl];
        int head = 0;
        float topv[TOPK]; int topi[TOPK];
        for (int r = 0; r < TOPK; ++r) {
          float bv = (head < TOPK) ? tv[c][head] : -1e30f;
          int bi = (head < TOPK) ? ti[c][head] : 0x7fffffff;
          #pragma unroll
          for (int off = 32; off > 0; off >>= 1) {
            float ov = __shfl_xor(bv, off, 64);
            int oi = __shfl_xor(bi, off, 64);
            if (ov > bv || (ov == bv && oi < bi)) { bv = ov; bi = oi; }
          }
          topv[r] = bv; topi[r] = bi;
          if (head < TOPK && ti[c][head] == bi) head++;
        }
        float m = topv[0];
        float wk[TOPK]; float wsum = 0.f;
        #pragma unroll
        for (int k = 0; k < TOPK; ++k) { wk[k] = expf((topv[k] - m) * INV_TEMP); wsum += wk[k]; }
        float inv_ws = 1.0f / wsum;
        float a0 = 0.f, a1 = 0.f;
        #pragma unroll
        for (int k = 0; k < TOPK; ++k) {
          const float* rr = res_raw + (size_t)topi[k] * H;
          a0 += wk[k] * rr[lane];
          a1 += wk[k] * rr[lane + 64];
        }
        feat[(size_t)n * H + lane] = a0 * inv_ws;
        feat[(size_t)n * H + lane + 64] = a1 * inv_ws;
      }
    }
    __syncthreads();   // before next group's normalize overwrites z1s
  }
}

// ---------------- fused 2-layer MLP ----------------
#define ROWS 32
#define RPT 16
__global__ __launch_bounds__(256) void mlp_kernel(
    const float* __restrict__ feat,
    const float* __restrict__ W1, const float* __restrict__ b1,
    const float* __restrict__ W2, const float* __restrict__ b2,
    float* __restrict__ out, int N)
{
  __shared__ __align__(16) float frow[ROWS][132];
  __shared__ __align__(16) float hrow[ROWS][132];
  int t = threadIdx.x;
  int row0 = blockIdx.x * ROWS;
  for (int k = t; k < ROWS * 32; k += 256) {
    int r = k >> 5, q = k & 31;
    float4 v = make_float4(0.f, 0.f, 0.f, 0.f);
    if (row0 + r < N) v = *(const float4*)(feat + (size_t)(row0 + r) * H + 4 * q);
    *(float4*)&frow[r][4 * q] = v;
  }
  __syncthreads();
  int i = t & 127;
  int rg = t >> 7;
  float acc[RPT];
  {
    float bias = b1[i];
    #pragma unroll
    for (int k = 0; k < RPT; ++k) acc[k] = bias;
    const float4* wv4 = (const float4*)(W1 + (size_t)i * H);
    for (int q = 0; q < 32; ++q) {
      float4 wv = wv4[q];
      #pragma unroll
      for (int k = 0; k < RPT; ++k) {
        float4 fv = *(const float4*)&frow[rg * RPT + k][4 * q];
        acc[k] += wv.x * fv.x + wv.y * fv.y + wv.z * fv.z + wv.w * fv.w;
      }
    }
    #pragma unroll
    for (int k = 0; k < RPT; ++k) hrow[rg * RPT + k][i] = fmaxf(acc[k], 0.f);
  }
  __syncthreads();
  {
    float bias = b2[i];
    #pragma unroll
    for (int k = 0; k < RPT; ++k) acc[k] = bias;
    const float4* wv4 = (const float4*)(W2 + (size_t)i * H);
    for (int q = 0; q < 32; ++q) {
      float4 wv = wv4[q];
      #pragma unroll
      for (int k = 0; k < RPT; ++k) {
        float4 fv = *(const float4*)&hrow[rg * RPT + k][4 * q];
        acc[k] += wv.x * fv.x + wv.y * fv.y + wv.z * fv.z + wv.w * fv.w;
      }
    }
    #pragma unroll
    for (int k = 0; k < RPT; ++k) {
      int r = row0 + rg * RPT + k;
      if (r < N) out[(size_t)r * H + i] = acc[k];
    }
  }
}

extern "C" void kernel_launch(void* const* d_in, const int* in_sizes, int n_in,
                              void* d_out, int out_size, void* d_ws, size_t ws_size,
                              hipStream_t stream) {
  const int* src = (const int*)d_in[0];
  const int* dst = (const int*)d_in[1];
  const int* rel = (const int*)d_in[2];
  const int* inv = (const int*)d_in[3];
  const float* ent   = (const float*)d_in[4];
  const float* rhead = (const float*)d_in[5];
  const float* rtail = (const float*)d_in[6];
  const float* resent = (const float*)d_in[7];
  const float* W1 = (const float*)d_in[8];
  const float* b1 = (const float*)d_in[9];
  const float* W2 = (const float*)d_in[10];
  const float* b2 = (const float*)d_in[11];
  int E = in_sizes[0];
  int N = in_sizes[4] / H;
  int NRES_ = in_sizes[7] / H;
  float* out = (float*)d_out;

  char* ws = (char*)d_ws;
  size_t padN = (((size_t)N * 4) + 255) & ~(size_t)255;
  int* in_deg  = (int*)ws;
  int* out_deg = (int*)(ws + padN);
  int* cursor  = (int*)(ws + 2 * padN);
  int* zcount  = (int*)(ws + 3 * padN);
  size_t base = 3 * padN + 256;
  int* offs = (int*)(ws + base);  base += (((size_t)(N + 1) * 4) + 255) & ~(size_t)255;
  int* zlist = (int*)(ws + base); base += padN;
  int* bucket = (int*)(ws + base); base += (((size_t)E * 4) + 255) & ~(size_t)255;
  float* z2t = (float*)(ws + base); base += (size_t)H * ZLD * 4;
  float* feat = out;  // reuse d_out as feat storage (per-row ownership in MLP)

  hipMemsetAsync(in_deg, 0, 3 * padN + 256, stream);

  deg_kernel<<<(E + 255) / 256, 256, 0, stream>>>(src, dst, in_deg, out_deg, E);
  scan_kernel<<<1, 1024, 0, stream>>>(in_deg, offs, N);
  fill_kernel<<<(E + 255) / 256, 256, 0, stream>>>(dst, rel, inv, offs, cursor, bucket, E);
  zerolist_kernel<<<(N + 255) / 256, 256, 0, stream>>>(in_deg, out_deg, zlist, zcount, N);
  norm_res_kernel<<<NRES_, 64, 0, stream>>>(resent, z2t, NRES_);
  gather_kernel<<<(N + 3) / 4, 256, 0, stream>>>(offs, bucket, rhead, rtail, feat, N);
  zero_emb_kernel<<<256, 256, 0, stream>>>(zlist, zcount, ent, z2t, resent, feat, NRES_);
  mlp_kernel<<<(N + ROWS - 1) / ROWS, 256, 0, stream>>>(feat, W1, b1, W2, b2, out, N);
}

// Round 3
// 310.532 us; speedup vs baseline: 1.2941x; 1.2941x over previous
//
#include <hip/hip_runtime.h>
#include <math.h>

#define H 128
#define TOPK 5
#define INV_TEMP 5.0f
#define ZLD 2048      // z2t column stride (>= NRES, pow2)
#define ZN 4          // zero-nodes per group
#define JQ 512        // j-columns per task (quarter of ZLD)

// ---------------- degree count ----------------
__global__ __launch_bounds__(256) void deg_kernel(
    const int* __restrict__ src, const int* __restrict__ dst,
    int* __restrict__ in_deg, int* __restrict__ out_deg, int E)
{
  int e = blockIdx.x * 256 + threadIdx.x;
  if (e < E) {
    atomicAdd(&in_deg[dst[e]], 1);
    atomicAdd(&out_deg[src[e]], 1);
  }
}

// ---------------- exclusive scan of in_deg -> offs[0..N] ----------------
__global__ __launch_bounds__(1024) void scan_kernel(
    const int* __restrict__ deg, int* __restrict__ offs, int n)
{
  __shared__ int sums[1024];
  int tid = threadIdx.x;
  int per = (((n + 1023) >> 10) + 3) & ~3;   // multiple of 4 for int4
  int start = tid * per;
  int end = min(start + per, n);
  int s = 0;
  int i = start;
  for (; i + 4 <= end; i += 4) {
    int4 v = *(const int4*)&deg[i];
    s += v.x + v.y + v.z + v.w;
  }
  for (; i < end; ++i) s += deg[i];
  sums[tid] = s;
  __syncthreads();
  for (int off = 1; off < 1024; off <<= 1) {
    int v = (tid >= off) ? sums[tid - off] : 0;
    __syncthreads();
    sums[tid] += v;
    __syncthreads();
  }
  int run = (tid == 0) ? 0 : sums[tid - 1];
  i = start;
  for (; i + 4 <= end; i += 4) {
    int4 v = *(const int4*)&deg[i];
    int4 o;
    o.x = run; run += v.x;
    o.y = run; run += v.y;
    o.z = run; run += v.z;
    o.w = run; run += v.w;
    *(int4*)&offs[i] = o;
  }
  for (; i < end; ++i) { offs[i] = run; run += deg[i]; }
  if (tid == 1023) offs[n] = sums[1023];
}

// ---------------- bucket fill (payload = rel | inv<<16) ----------------
__global__ __launch_bounds__(256) void fill_kernel(
    const int* __restrict__ dst, const int* __restrict__ rel, const int* __restrict__ inv,
    const int* __restrict__ offs, int* __restrict__ cursor, int* __restrict__ bucket, int E)
{
  int e = blockIdx.x * 256 + threadIdx.x;
  if (e < E) {
    int d = dst[e];
    int pos = offs[d] + atomicAdd(&cursor[d], 1);
    bucket[pos] = rel[e] | (inv[e] << 16);
  }
}

// ---------------- zero-total-degree node list ----------------
__global__ __launch_bounds__(256) void zerolist_kernel(
    const int* __restrict__ in_deg, const int* __restrict__ out_deg,
    int* __restrict__ zlist, int* __restrict__ zcount, int N)
{
  int n = blockIdx.x * 256 + threadIdx.x;
  if (n < N && (in_deg[n] + out_deg[n]) == 0) {
    int p = atomicAdd(zcount, 1);
    zlist[p] = n;
  }
}

// ---------------- l2-normalize res_ent_emb rows -> TRANSPOSED z2t[k][j] ----------------
__global__ __launch_bounds__(64) void norm_res_kernel(
    const float* __restrict__ res, float* __restrict__ z2t, int NRES_)
{
  int r = blockIdx.x;
  int lane = threadIdx.x;
  float x0 = res[(size_t)r * H + lane];
  float x1 = res[(size_t)r * H + lane + 64];
  float ss = x0 * x0 + x1 * x1;
  #pragma unroll
  for (int off = 32; off > 0; off >>= 1) ss += __shfl_xor(ss, off, 64);
  float iv = 1.0f / fmaxf(sqrtf(ss), 1e-12f);
  z2t[(size_t)lane * ZLD + r] = x0 * iv;
  z2t[(size_t)(lane + 64) * ZLD + r] = x1 * iv;
}

// ---------------- per-node mean gather (one wave per node) ----------------
__global__ __launch_bounds__(256) void gather_kernel(
    const int* __restrict__ offs, const int* __restrict__ bucket,
    const float* __restrict__ rhead, const float* __restrict__ rtail,
    float* __restrict__ feat, int N)
{
  int gid = blockIdx.x * 256 + threadIdx.x;
  int wid = gid >> 6;
  int lane = gid & 63;
  if (wid >= N) return;
  int b = offs[wid], e2 = offs[wid + 1];
  float a0 = 0.f, a1 = 0.f;
  for (int p = b; p < e2; ++p) {
    int pay = bucket[p];
    int r = pay & 0xFFFF;
    const float* row = ((pay >> 16) ? rhead : rtail) + (size_t)r * H;
    a0 += row[lane];
    a1 += row[lane + 64];
  }
  int deg = e2 - b;
  float sc = 1.0f / (float)(deg > 0 ? deg : 1);
  feat[(size_t)wid * H + lane] = a0 * sc;
  feat[(size_t)wid * H + lane + 64] = a1 * sc;
}

// ---------------- zero-node sims + partial top-5 per (group, j-quarter) ----------------
// Task = (group of 4 zero-nodes) x (512-wide j quarter). ~2048 tasks for
// Z=2048 -> 8 blocks/CU, latency hidden. Partial top-5 written per
// (task, node); merged by zmerge_kernel.
__global__ __launch_bounds__(256) void zero_sims_kernel(
    const int* __restrict__ zlist, const int* __restrict__ zcount,
    const float* __restrict__ ent, const float* __restrict__ z2t,
    float2* __restrict__ partials, int NRES_)
{
  __shared__ __align__(16) float z1s[ZN * H];    // 2 KB
  __shared__ __align__(8) float sims[ZN * JQ];   // 8 KB
  int t = threadIdx.x;
  int w = t >> 6;
  int lane = t & 63;
  int Z = *zcount;
  int ntasks = ((Z + ZN - 1) / ZN) << 2;
  for (int task = blockIdx.x; task < ntasks; task += gridDim.x) {
    int g = task >> 2, q = task & 3;
    int zi0 = g * ZN;
    int nv = min(ZN, Z - zi0);
    // ---- normalize z1 row: wave w -> node w ----
    {
      float x0 = 0.f, x1 = 0.f;
      if (w < nv) {
        int n = zlist[zi0 + w];
        x0 = ent[(size_t)n * H + lane];
        x1 = ent[(size_t)n * H + lane + 64];
        float ss = x0 * x0 + x1 * x1;
        #pragma unroll
        for (int off = 32; off > 0; off >>= 1) ss += __shfl_xor(ss, off, 64);
        float iv = 1.0f / fmaxf(sqrtf(ss), 1e-12f);
        x0 *= iv; x1 *= iv;
      }
      z1s[w * H + lane] = x0;
      z1s[w * H + lane + 64] = x1;
    }
    __syncthreads();
    // ---- sims: thread t owns j-columns (2t, 2t+1) of this quarter ----
    {
      int jl0 = 2 * t;
      const float* zcol = z2t + (size_t)q * JQ + jl0;
      float acc0[ZN], acc1[ZN];
      #pragma unroll
      for (int n = 0; n < ZN; ++n) { acc0[n] = 0.f; acc1[n] = 0.f; }
      #pragma unroll 2
      for (int k = 0; k < H; k += 4) {
        float2 a[4];
        #pragma unroll
        for (int kk = 0; kk < 4; ++kk)
          a[kk] = *(const float2*)(zcol + (size_t)(k + kk) * ZLD);
        #pragma unroll
        for (int n = 0; n < ZN; ++n) {
          float4 zv = *(const float4*)&z1s[n * H + k];
          acc0[n] += zv.x * a[0].x + zv.y * a[1].x + zv.z * a[2].x + zv.w * a[3].x;
          acc1[n] += zv.x * a[0].y + zv.y * a[1].y + zv.z * a[2].y + zv.w * a[3].y;
        }
      }
      int j0 = q * JQ + jl0;
      #pragma unroll
      for (int n = 0; n < ZN; ++n) {
        float v0 = (j0 < NRES_) ? acc0[n] : -1e30f;
        float v1 = (j0 + 1 < NRES_) ? acc1[n] : -1e30f;
        *(float2*)&sims[n * JQ + jl0] = make_float2(v0, v1);
      }
    }
    __syncthreads();
    // ---- per-wave top-5 of this quarter (wave w -> node w) ----
    if (w < nv) {
      float tv[TOPK]; int ti[TOPK];
      #pragma unroll
      for (int k = 0; k < TOPK; ++k) { tv[k] = -1e30f; ti[k] = 0x7fffffff; }
      #pragma unroll
      for (int i = 0; i < JQ / 64; ++i) {
        int jl = i * 64 + lane;
        float s = sims[w * JQ + jl];
        int j = q * JQ + jl;
        if (s > tv[TOPK - 1] || (s == tv[TOPK - 1] && j < ti[TOPK - 1])) {
          tv[TOPK - 1] = s; ti[TOPK - 1] = j;
          #pragma unroll
          for (int k = TOPK - 1; k > 0; --k) {
            if (tv[k] > tv[k - 1] || (tv[k] == tv[k - 1] && ti[k] < ti[k - 1])) {
              float a = tv[k]; tv[k] = tv[k - 1]; tv[k - 1] = a;
              int bI = ti[k]; ti[k] = ti[k - 1]; ti[k - 1] = bI;
            }
          }
        }
      }
      // 5 rounds of cross-lane argmax; winner removed via static compares
      #pragma unroll
      for (int r = 0; r < TOPK; ++r) {
        float bv = tv[0]; int bi = ti[0];
        #pragma unroll
        for (int k = 1; k < TOPK; ++k)
          if (tv[k] > bv || (tv[k] == bv && ti[k] < bi)) { bv = tv[k]; bi = ti[k]; }
        #pragma unroll
        for (int off = 32; off > 0; off >>= 1) {
          float ov = __shfl_xor(bv, off, 64);
          int oi = __shfl_xor(bi, off, 64);
          if (ov > bv || (ov == bv && oi < bi)) { bv = ov; bi = oi; }
        }
        if (lane == r)
          partials[((size_t)task * ZN + w) * TOPK + r] =
              make_float2(bv, __int_as_float(bi));
        #pragma unroll
        for (int k = 0; k < TOPK; ++k)
          if (ti[k] == bi) tv[k] = -1e30f;
      }
    }
    __syncthreads();
  }
}

// ---------------- merge 4 quarter top-5s -> softmax -> weighted sum ----------------
__global__ __launch_bounds__(256) void zmerge_kernel(
    const int* __restrict__ zlist, const int* __restrict__ zcount,
    const float2* __restrict__ partials, const float* __restrict__ res_raw,
    float* __restrict__ feat, int NRES_)
{
  int gid = blockIdx.x * 256 + threadIdx.x;
  int wid = gid >> 6;
  int lane = gid & 63;
  int nw = (gridDim.x * 256) >> 6;
  int Z = *zcount;
  for (int nz = wid; nz < Z; nz += nw) {
    int g = nz >> 2, w = nz & 3;
    float v = -1e30f; int idx = 0x7fffffff;
    if (lane < 4 * TOPK) {
      int q = lane / TOPK, k = lane - q * TOPK;
      float2 p = partials[((size_t)(g * 4 + q) * ZN + w) * TOPK + k];
      v = p.x; idx = __float_as_int(p.y);
    }
    bool used = false;
    float m = 0.f, wsum = 0.f, a0 = 0.f, a1 = 0.f;
    #pragma unroll
    for (int r = 0; r < TOPK; ++r) {
      float bv = used ? -1e31f : v;
      int bi = used ? 0x7fffffff : idx;
      #pragma unroll
      for (int off = 32; off > 0; off >>= 1) {
        float ov = __shfl_xor(bv, off, 64);
        int oi = __shfl_xor(bi, off, 64);
        if (ov > bv || (ov == bv && oi < bi)) { bv = ov; bi = oi; }
      }
      if (r == 0) m = bv;
      bool ok = (unsigned)bi < (unsigned)NRES_;
      float wk = ok ? expf((bv - m) * INV_TEMP) : 0.f;
      wsum += wk;
      const float* rr = res_raw + (size_t)(ok ? bi : 0) * H;
      a0 += wk * rr[lane];
      a1 += wk * rr[lane + 64];
      if (idx == bi) used = true;
    }
    float inv_ws = 1.0f / wsum;
    int n = zlist[nz];
    feat[(size_t)n * H + lane] = a0 * inv_ws;
    feat[(size_t)n * H + lane + 64] = a1 * inv_ws;
  }
}

// ---------------- fused 2-layer MLP ----------------
#define ROWS 32
#define RPT 16
__global__ __launch_bounds__(256) void mlp_kernel(
    const float* __restrict__ feat,
    const float* __restrict__ W1, const float* __restrict__ b1,
    const float* __restrict__ W2, const float* __restrict__ b2,
    float* __restrict__ out, int N)
{
  __shared__ __align__(16) float frow[ROWS][132];
  __shared__ __align__(16) float hrow[ROWS][132];
  int t = threadIdx.x;
  int row0 = blockIdx.x * ROWS;
  for (int k = t; k < ROWS * 32; k += 256) {
    int r = k >> 5, q = k & 31;
    float4 v = make_float4(0.f, 0.f, 0.f, 0.f);
    if (row0 + r < N) v = *(const float4*)(feat + (size_t)(row0 + r) * H + 4 * q);
    *(float4*)&frow[r][4 * q] = v;
  }
  __syncthreads();
  int i = t & 127;
  int rg = t >> 7;
  float acc[RPT];
  {
    float bias = b1[i];
    #pragma unroll
    for (int k = 0; k < RPT; ++k) acc[k] = bias;
    const float4* wv4 = (const float4*)(W1 + (size_t)i * H);
    for (int q = 0; q < 32; ++q) {
      float4 wv = wv4[q];
      #pragma unroll
      for (int k = 0; k < RPT; ++k) {
        float4 fv = *(const float4*)&frow[rg * RPT + k][4 * q];
        acc[k] += wv.x * fv.x + wv.y * fv.y + wv.z * fv.z + wv.w * fv.w;
      }
    }
    #pragma unroll
    for (int k = 0; k < RPT; ++k) hrow[rg * RPT + k][i] = fmaxf(acc[k], 0.f);
  }
  __syncthreads();
  {
    float bias = b2[i];
    #pragma unroll
    for (int k = 0; k < RPT; ++k) acc[k] = bias;
    const float4* wv4 = (const float4*)(W2 + (size_t)i * H);
    for (int q = 0; q < 32; ++q) {
      float4 wv = wv4[q];
      #pragma unroll
      for (int k = 0; k < RPT; ++k) {
        float4 fv = *(const float4*)&hrow[rg * RPT + k][4 * q];
        acc[k] += wv.x * fv.x + wv.y * fv.y + wv.z * fv.z + wv.w * fv.w;
      }
    }
    #pragma unroll
    for (int k = 0; k < RPT; ++k) {
      int r = row0 + rg * RPT + k;
      if (r < N) out[(size_t)r * H + i] = acc[k];
    }
  }
}

extern "C" void kernel_launch(void* const* d_in, const int* in_sizes, int n_in,
                              void* d_out, int out_size, void* d_ws, size_t ws_size,
                              hipStream_t stream) {
  const int* src = (const int*)d_in[0];
  const int* dst = (const int*)d_in[1];
  const int* rel = (const int*)d_in[2];
  const int* inv = (const int*)d_in[3];
  const float* ent   = (const float*)d_in[4];
  const float* rhead = (const float*)d_in[5];
  const float* rtail = (const float*)d_in[6];
  const float* resent = (const float*)d_in[7];
  const float* W1 = (const float*)d_in[8];
  const float* b1 = (const float*)d_in[9];
  const float* W2 = (const float*)d_in[10];
  const float* b2 = (const float*)d_in[11];
  int E = in_sizes[0];
  int N = in_sizes[4] / H;
  int NRES_ = in_sizes[7] / H;
  float* out = (float*)d_out;

  char* ws = (char*)d_ws;
  size_t padN = (((size_t)N * 4) + 255) & ~(size_t)255;
  int* in_deg  = (int*)ws;
  int* out_deg = (int*)(ws + padN);
  int* cursor  = (int*)(ws + 2 * padN);
  int* zcount  = (int*)(ws + 3 * padN);
  size_t base = 3 * padN + 256;
  int* offs = (int*)(ws + base);  base += (((size_t)(N + 1) * 4) + 255) & ~(size_t)255;
  int* zlist = (int*)(ws + base); base += padN;
  int* bucket = (int*)(ws + base); base += (((size_t)E * 4) + 255) & ~(size_t)255;
  float* z2t = (float*)(ws + base); base += (size_t)H * ZLD * 4;
  float2* partials = (float2*)(ws + base);  // ~40 B per zero node actually touched
  float* feat = out;  // reuse d_out as feat storage (per-row ownership in MLP)

  hipMemsetAsync(in_deg, 0, 3 * padN + 256, stream);

  deg_kernel<<<(E + 255) / 256, 256, 0, stream>>>(src, dst, in_deg, out_deg, E);
  scan_kernel<<<1, 1024, 0, stream>>>(in_deg, offs, N);
  fill_kernel<<<(E + 255) / 256, 256, 0, stream>>>(dst, rel, inv, offs, cursor, bucket, E);
  zerolist_kernel<<<(N + 255) / 256, 256, 0, stream>>>(in_deg, out_deg, zlist, zcount, N);
  norm_res_kernel<<<NRES_, 64, 0, stream>>>(resent, z2t, NRES_);
  gather_kernel<<<(N + 3) / 4, 256, 0, stream>>>(offs, bucket, rhead, rtail, feat, N);
  zero_sims_kernel<<<2048, 256, 0, stream>>>(zlist, zcount, ent, z2t, partials, NRES_);
  zmerge_kernel<<<128, 256, 0, stream>>>(zlist, zcount, partials, resent, out, NRES_);
  mlp_kernel<<<(N + ROWS - 1) / ROWS, 256, 0, stream>>>(feat, W1, b1, W2, b2, out, N);
}

// Round 4
// 259.280 us; speedup vs baseline: 1.5499x; 1.1977x over previous
//
#include <hip/hip_runtime.h>
#include <math.h>

#define H 128
#define TOPK 5
#define INV_TEMP 5.0f
#define ZLD 2048      // z2t column stride (>= NRES, pow2)
#define ZN 4          // zero-nodes per group
#define JQ 512        // j-columns per task (quarter of ZLD)

typedef __attribute__((ext_vector_type(8))) short short8;
typedef __attribute__((ext_vector_type(4))) float f32x4;

__device__ __forceinline__ unsigned bf16_rne(float x) {
  unsigned u = __float_as_uint(x);
  return (u + 0x7FFFu + ((u >> 16) & 1u)) >> 16;
}
__device__ __forceinline__ unsigned pk_bf16(float lo, float hi) {
  return bf16_rne(lo) | (bf16_rne(hi) << 16);
}

// ---------------- degree count ----------------
__global__ __launch_bounds__(256) void deg_kernel(
    const int* __restrict__ src, const int* __restrict__ dst,
    int* __restrict__ in_deg, int* __restrict__ out_deg, int E)
{
  int e = blockIdx.x * 256 + threadIdx.x;
  if (e < E) {
    atomicAdd(&in_deg[dst[e]], 1);
    atomicAdd(&out_deg[src[e]], 1);
  }
}

// ---------------- exclusive scan of in_deg -> offs[0..N] ----------------
__global__ __launch_bounds__(1024) void scan_kernel(
    const int* __restrict__ deg, int* __restrict__ offs, int n)
{
  __shared__ int sums[1024];
  int tid = threadIdx.x;
  int per = (((n + 1023) >> 10) + 3) & ~3;   // multiple of 4 for int4
  int start = tid * per;
  int end = min(start + per, n);
  int s = 0;
  int i = start;
  for (; i + 4 <= end; i += 4) {
    int4 v = *(const int4*)&deg[i];
    s += v.x + v.y + v.z + v.w;
  }
  for (; i < end; ++i) s += deg[i];
  sums[tid] = s;
  __syncthreads();
  for (int off = 1; off < 1024; off <<= 1) {
    int v = (tid >= off) ? sums[tid - off] : 0;
    __syncthreads();
    sums[tid] += v;
    __syncthreads();
  }
  int run = (tid == 0) ? 0 : sums[tid - 1];
  i = start;
  for (; i + 4 <= end; i += 4) {
    int4 v = *(const int4*)&deg[i];
    int4 o;
    o.x = run; run += v.x;
    o.y = run; run += v.y;
    o.z = run; run += v.z;
    o.w = run; run += v.w;
    *(int4*)&offs[i] = o;
  }
  for (; i < end; ++i) { offs[i] = run; run += deg[i]; }
  if (tid == 1023) offs[n] = sums[1023];
}

// ---------------- bucket fill (payload = rel | inv<<16) ----------------
__global__ __launch_bounds__(256) void fill_kernel(
    const int* __restrict__ dst, const int* __restrict__ rel, const int* __restrict__ inv,
    const int* __restrict__ offs, int* __restrict__ cursor, int* __restrict__ bucket, int E)
{
  int e = blockIdx.x * 256 + threadIdx.x;
  if (e < E) {
    int d = dst[e];
    int pos = offs[d] + atomicAdd(&cursor[d], 1);
    bucket[pos] = rel[e] | (inv[e] << 16);
  }
}

// ---------------- prep: zero-degree node list + W1/W2 -> bf16 ----------------
__global__ __launch_bounds__(256) void prep_kernel(
    const int* __restrict__ in_deg, const int* __restrict__ out_deg,
    int* __restrict__ zlist, int* __restrict__ zcount, int N,
    const float* __restrict__ W1, const float* __restrict__ W2,
    unsigned short* __restrict__ W1b, unsigned short* __restrict__ W2b)
{
  int nbz = (N + 255) >> 8;
  int b = blockIdx.x;
  if (b < nbz) {
    int n = b * 256 + threadIdx.x;
    if (n < N && (in_deg[n] + out_deg[n]) == 0) {
      int p = atomicAdd(zcount, 1);
      zlist[p] = n;
    }
  } else {
    int b2 = b - nbz;              // 0..31
    const float* Wsrc = (b2 < 16) ? W1 : W2;
    unsigned short* Wdst = (b2 < 16) ? W1b : W2b;
    int base = (b2 & 15) * 1024 + threadIdx.x * 4;
    float4 v = *(const float4*)&Wsrc[base];
    uint2 p = make_uint2(pk_bf16(v.x, v.y), pk_bf16(v.z, v.w));
    *(uint2*)&Wdst[base] = p;
  }
}

// ---------------- l2-normalize res_ent_emb rows -> TRANSPOSED z2t[k][j] ----------------
__global__ __launch_bounds__(64) void norm_res_kernel(
    const float* __restrict__ res, float* __restrict__ z2t, int NRES_)
{
  int r = blockIdx.x;
  int lane = threadIdx.x;
  float x0 = res[(size_t)r * H + lane];
  float x1 = res[(size_t)r * H + lane + 64];
  float ss = x0 * x0 + x1 * x1;
  #pragma unroll
  for (int off = 32; off > 0; off >>= 1) ss += __shfl_xor(ss, off, 64);
  float iv = 1.0f / fmaxf(sqrtf(ss), 1e-12f);
  z2t[(size_t)lane * ZLD + r] = x0 * iv;
  z2t[(size_t)(lane + 64) * ZLD + r] = x1 * iv;
}

// ---------------- per-node mean gather (one wave per node) ----------------
__global__ __launch_bounds__(256) void gather_kernel(
    const int* __restrict__ offs, const int* __restrict__ bucket,
    const float* __restrict__ rhead, const float* __restrict__ rtail,
    float* __restrict__ feat, int N)
{
  int gid = blockIdx.x * 256 + threadIdx.x;
  int wid = gid >> 6;
  int lane = gid & 63;
  if (wid >= N) return;
  int b = offs[wid], e2 = offs[wid + 1];
  float a0 = 0.f, a1 = 0.f;
  for (int p = b; p < e2; ++p) {
    int pay = bucket[p];
    int r = pay & 0xFFFF;
    const float* row = ((pay >> 16) ? rhead : rtail) + (size_t)r * H;
    a0 += row[lane];
    a1 += row[lane + 64];
  }
  int deg = e2 - b;
  float sc = 1.0f / (float)(deg > 0 ? deg : 1);
  feat[(size_t)wid * H + lane] = a0 * sc;
  feat[(size_t)wid * H + lane + 64] = a1 * sc;
}

// ---------------- zero-node sims + partial top-5 per (group, j-quarter) ----------------
__global__ __launch_bounds__(256) void zero_sims_kernel(
    const int* __restrict__ zlist, const int* __restrict__ zcount,
    const float* __restrict__ ent, const float* __restrict__ z2t,
    float2* __restrict__ partials, int NRES_)
{
  __shared__ __align__(16) float z1s[ZN * H];    // 2 KB
  __shared__ __align__(8) float sims[ZN * JQ];   // 8 KB
  int t = threadIdx.x;
  int w = t >> 6;
  int lane = t & 63;
  int Z = *zcount;
  int ntasks = ((Z + ZN - 1) / ZN) << 2;
  for (int task = blockIdx.x; task < ntasks; task += gridDim.x) {
    int g = task >> 2, q = task & 3;
    int zi0 = g * ZN;
    int nv = min(ZN, Z - zi0);
    {
      float x0 = 0.f, x1 = 0.f;
      if (w < nv) {
        int n = zlist[zi0 + w];
        x0 = ent[(size_t)n * H + lane];
        x1 = ent[(size_t)n * H + lane + 64];
        float ss = x0 * x0 + x1 * x1;
        #pragma unroll
        for (int off = 32; off > 0; off >>= 1) ss += __shfl_xor(ss, off, 64);
        float iv = 1.0f / fmaxf(sqrtf(ss), 1e-12f);
        x0 *= iv; x1 *= iv;
      }
      z1s[w * H + lane] = x0;
      z1s[w * H + lane + 64] = x1;
    }
    __syncthreads();
    {
      int jl0 = 2 * t;
      const float* zcol = z2t + (size_t)q * JQ + jl0;
      float acc0[ZN], acc1[ZN];
      #pragma unroll
      for (int n = 0; n < ZN; ++n) { acc0[n] = 0.f; acc1[n] = 0.f; }
      #pragma unroll 2
      for (int k = 0; k < H; k += 4) {
        float2 a[4];
        #pragma unroll
        for (int kk = 0; kk < 4; ++kk)
          a[kk] = *(const float2*)(zcol + (size_t)(k + kk) * ZLD);
        #pragma unroll
        for (int n = 0; n < ZN; ++n) {
          float4 zv = *(const float4*)&z1s[n * H + k];
          acc0[n] += zv.x * a[0].x + zv.y * a[1].x + zv.z * a[2].x + zv.w * a[3].x;
          acc1[n] += zv.x * a[0].y + zv.y * a[1].y + zv.z * a[2].y + zv.w * a[3].y;
        }
      }
      int j0 = q * JQ + jl0;
      #pragma unroll
      for (int n = 0; n < ZN; ++n) {
        float v0 = (j0 < NRES_) ? acc0[n] : -1e30f;
        float v1 = (j0 + 1 < NRES_) ? acc1[n] : -1e30f;
        *(float2*)&sims[n * JQ + jl0] = make_float2(v0, v1);
      }
    }
    __syncthreads();
    if (w < nv) {
      float tv[TOPK]; int ti[TOPK];
      #pragma unroll
      for (int k = 0; k < TOPK; ++k) { tv[k] = -1e30f; ti[k] = 0x7fffffff; }
      #pragma unroll
      for (int i = 0; i < JQ / 64; ++i) {
        int jl = i * 64 + lane;
        float s = sims[w * JQ + jl];
        int j = q * JQ + jl;
        if (s > tv[TOPK - 1] || (s == tv[TOPK - 1] && j < ti[TOPK - 1])) {
          tv[TOPK - 1] = s; ti[TOPK - 1] = j;
          #pragma unroll
          for (int k = TOPK - 1; k > 0; --k) {
            if (tv[k] > tv[k - 1] || (tv[k] == tv[k - 1] && ti[k] < ti[k - 1])) {
              float a = tv[k]; tv[k] = tv[k - 1]; tv[k - 1] = a;
              int bI = ti[k]; ti[k] = ti[k - 1]; ti[k - 1] = bI;
            }
          }
        }
      }
      #pragma unroll
      for (int r = 0; r < TOPK; ++r) {
        float bv = tv[0]; int bi = ti[0];
        #pragma unroll
        for (int k = 1; k < TOPK; ++k)
          if (tv[k] > bv || (tv[k] == bv && ti[k] < bi)) { bv = tv[k]; bi = ti[k]; }
        #pragma unroll
        for (int off = 32; off > 0; off >>= 1) {
          float ov = __shfl_xor(bv, off, 64);
          int oi = __shfl_xor(bi, off, 64);
          if (ov > bv || (ov == bv && oi < bi)) { bv = ov; bi = oi; }
        }
        if (lane == r)
          partials[((size_t)task * ZN + w) * TOPK + r] =
              make_float2(bv, __int_as_float(bi));
        #pragma unroll
        for (int k = 0; k < TOPK; ++k)
          if (ti[k] == bi) tv[k] = -1e30f;
      }
    }
    __syncthreads();
  }
}

// ---------------- merge 4 quarter top-5s -> softmax -> weighted sum ----------------
__global__ __launch_bounds__(256) void zmerge_kernel(
    const int* __restrict__ zlist, const int* __restrict__ zcount,
    const float2* __restrict__ partials, const float* __restrict__ res_raw,
    float* __restrict__ feat, int NRES_)
{
  int gid = blockIdx.x * 256 + threadIdx.x;
  int wid = gid >> 6;
  int lane = gid & 63;
  int nw = (gridDim.x * 256) >> 6;
  int Z = *zcount;
  for (int nz = wid; nz < Z; nz += nw) {
    int g = nz >> 2, w = nz & 3;
    float v = -1e30f; int idx = 0x7fffffff;
    if (lane < 4 * TOPK) {
      int q = lane / TOPK, k = lane - q * TOPK;
      float2 p = partials[((size_t)(g * 4 + q) * ZN + w) * TOPK + k];
      v = p.x; idx = __float_as_int(p.y);
    }
    bool used = false;
    float m = 0.f, wsum = 0.f, a0 = 0.f, a1 = 0.f;
    #pragma unroll
    for (int r = 0; r < TOPK; ++r) {
      float bv = used ? -1e31f : v;
      int bi = used ? 0x7fffffff : idx;
      #pragma unroll
      for (int off = 32; off > 0; off >>= 1) {
        float ov = __shfl_xor(bv, off, 64);
        int oi = __shfl_xor(bi, off, 64);
        if (ov > bv || (ov == bv && oi < bi)) { bv = ov; bi = oi; }
      }
      if (r == 0) m = bv;
      bool ok = (unsigned)bi < (unsigned)NRES_;
      float wk = ok ? expf((bv - m) * INV_TEMP) : 0.f;
      wsum += wk;
      const float* rr = res_raw + (size_t)(ok ? bi : 0) * H;
      a0 += wk * rr[lane];
      a1 += wk * rr[lane + 64];
      if (idx == bi) used = true;
    }
    float inv_ws = 1.0f / wsum;
    int n = zlist[nz];
    feat[(size_t)n * H + lane] = a0 * inv_ws;
    feat[(size_t)n * H + lane + 64] = a1 * inv_ws;
  }
}

// ---------------- fused 2-layer MLP via bf16 MFMA ----------------
// 64 rows/block, 4 waves; wave w owns rows [16w,16w+16) x all 128 cols.
// feat staged f32 in LDS with 16B-slot XOR swizzle; A-frags converted to
// bf16 in-register; W1b/W2b pre-converted bf16 (L2-resident); bias = C-init.
__global__ __launch_bounds__(256) void mlp_kernel(
    const float* __restrict__ feat,
    const unsigned short* __restrict__ W1b, const float* __restrict__ b1,
    const unsigned short* __restrict__ W2b, const float* __restrict__ b2,
    float* __restrict__ out, int N)
{
  __shared__ float lds[64 * 128];   // 32 KB
  char* ldsb = (char*)lds;
  int t = threadIdx.x;
  int lane = t & 63;
  int w = t >> 6;
  int row0 = blockIdx.x * 64;

  // stage feat tile (coalesced global, swizzled LDS)
  for (int idx = t; idx < 64 * 32; idx += 256) {
    int r = idx >> 5, q = idx & 31;
    float4 v = make_float4(0.f, 0.f, 0.f, 0.f);
    if (row0 + r < N) v = *(const float4*)&feat[(size_t)(row0 + r) * H + q * 4];
    int byte = (r * 512 + q * 16) ^ ((r & 7) << 4);
    *(float4*)(ldsb + byte) = v;
  }
  __syncthreads();

  int m0 = w * 16;
  int col = lane & 15;
  int kg = lane >> 4;
  int am = m0 + col;                 // A-frag row
  int aswz = (am & 7) << 4;

  float bias1[8], bias2[8];
  #pragma unroll
  for (int nt = 0; nt < 8; ++nt) {
    bias1[nt] = b1[nt * 16 + col];
    bias2[nt] = b2[nt * 16 + col];
  }

  short8 afr[4];
  f32x4 acc[8];

  // ---- layer 1 ----
  #pragma unroll
  for (int ks = 0; ks < 4; ++ks) {
    int base = am * 512 + ks * 128 + kg * 32;
    float4 lo = *(float4*)(ldsb + (base ^ aswz));
    float4 hi = *(float4*)(ldsb + ((base + 16) ^ aswz));
    union { unsigned u[4]; short8 s; } cv;
    cv.u[0] = pk_bf16(lo.x, lo.y); cv.u[1] = pk_bf16(lo.z, lo.w);
    cv.u[2] = pk_bf16(hi.x, hi.y); cv.u[3] = pk_bf16(hi.z, hi.w);
    afr[ks] = cv.s;
  }
  #pragma unroll
  for (int nt = 0; nt < 8; ++nt) {
    f32x4 a; a[0] = a[1] = a[2] = a[3] = bias1[nt];
    acc[nt] = a;
    const unsigned short* wrow = W1b + (size_t)(nt * 16 + col) * H + kg * 8;
    #pragma unroll
    for (int ks = 0; ks < 4; ++ks) {
      union { int4 i; short8 s; } bv;
      bv.i = *(const int4*)(wrow + ks * 32);
      acc[nt] = __builtin_amdgcn_mfma_f32_16x16x32_bf16(afr[ks], bv.s, acc[nt], 0, 0, 0);
    }
  }
  __syncthreads();
  // relu + write h (f32, swizzled)
  #pragma unroll
  for (int nt = 0; nt < 8; ++nt) {
    int n = nt * 16 + col;
    #pragma unroll
    for (int r = 0; r < 4; ++r) {
      int m = m0 + kg * 4 + r;
      int byte = (m * 512 + n * 4) ^ ((m & 7) << 4);
      *(float*)(ldsb + byte) = fmaxf(acc[nt][r], 0.f);
    }
  }
  __syncthreads();

  // ---- layer 2 ----
  #pragma unroll
  for (int ks = 0; ks < 4; ++ks) {
    int base = am * 512 + ks * 128 + kg * 32;
    float4 lo = *(float4*)(ldsb + (base ^ aswz));
    float4 hi = *(float4*)(ldsb + ((base + 16) ^ aswz));
    union { unsigned u[4]; short8 s; } cv;
    cv.u[0] = pk_bf16(lo.x, lo.y); cv.u[1] = pk_bf16(lo.z, lo.w);
    cv.u[2] = pk_bf16(hi.x, hi.y); cv.u[3] = pk_bf16(hi.z, hi.w);
    afr[ks] = cv.s;
  }
  #pragma unroll
  for (int nt = 0; nt < 8; ++nt) {
    f32x4 a; a[0] = a[1] = a[2] = a[3] = bias2[nt];
    acc[nt] = a;
    const unsigned short* wrow = W2b + (size_t)(nt * 16 + col) * H + kg * 8;
    #pragma unroll
    for (int ks = 0; ks < 4; ++ks) {
      union { int4 i; short8 s; } bv;
      bv.i = *(const int4*)(wrow + ks * 32);
      acc[nt] = __builtin_amdgcn_mfma_f32_16x16x32_bf16(afr[ks], bv.s, acc[nt], 0, 0, 0);
    }
  }
  // store
  #pragma unroll
  for (int nt = 0; nt < 8; ++nt) {
    int n = nt * 16 + col;
    #pragma unroll
    for (int r = 0; r < 4; ++r) {
      int m = row0 + m0 + kg * 4 + r;
      if (m < N) out[(size_t)m * H + n] = acc[nt][r];
    }
  }
}

extern "C" void kernel_launch(void* const* d_in, const int* in_sizes, int n_in,
                              void* d_out, int out_size, void* d_ws, size_t ws_size,
                              hipStream_t stream) {
  const int* src = (const int*)d_in[0];
  const int* dst = (const int*)d_in[1];
  const int* rel = (const int*)d_in[2];
  const int* inv = (const int*)d_in[3];
  const float* ent   = (const float*)d_in[4];
  const float* rhead = (const float*)d_in[5];
  const float* rtail = (const float*)d_in[6];
  const float* resent = (const float*)d_in[7];
  const float* W1 = (const float*)d_in[8];
  const float* b1 = (const float*)d_in[9];
  const float* W2 = (const float*)d_in[10];
  const float* b2 = (const float*)d_in[11];
  int E = in_sizes[0];
  int N = in_sizes[4] / H;
  int NRES_ = in_sizes[7] / H;
  float* out = (float*)d_out;

  char* ws = (char*)d_ws;
  size_t padN = (((size_t)N * 4) + 255) & ~(size_t)255;
  int* in_deg  = (int*)ws;
  int* out_deg = (int*)(ws + padN);
  int* cursor  = (int*)(ws + 2 * padN);
  int* zcount  = (int*)(ws + 3 * padN);
  size_t base = 3 * padN + 256;
  int* offs = (int*)(ws + base);  base += (((size_t)(N + 1) * 4) + 255) & ~(size_t)255;
  int* zlist = (int*)(ws + base); base += padN;
  int* bucket = (int*)(ws + base); base += (((size_t)E * 4) + 255) & ~(size_t)255;
  float* z2t = (float*)(ws + base); base += (size_t)H * ZLD * 4;
  unsigned short* W1b = (unsigned short*)(ws + base); base += (size_t)H * H * 2;
  unsigned short* W2b = (unsigned short*)(ws + base); base += (size_t)H * H * 2;
  float2* partials = (float2*)(ws + base);
  float* feat = out;  // reuse d_out as feat storage (per-row ownership in MLP)

  hipMemsetAsync(in_deg, 0, 3 * padN + 256, stream);

  int nbz = (N + 255) / 256;
  deg_kernel<<<(E + 255) / 256, 256, 0, stream>>>(src, dst, in_deg, out_deg, E);
  scan_kernel<<<1, 1024, 0, stream>>>(in_deg, offs, N);
  fill_kernel<<<(E + 255) / 256, 256, 0, stream>>>(dst, rel, inv, offs, cursor, bucket, E);
  prep_kernel<<<nbz + 32, 256, 0, stream>>>(in_deg, out_deg, zlist, zcount, N, W1, W2, W1b, W2b);
  norm_res_kernel<<<NRES_, 64, 0, stream>>>(resent, z2t, NRES_);
  gather_kernel<<<(N + 3) / 4, 256, 0, stream>>>(offs, bucket, rhead, rtail, feat, N);
  zero_sims_kernel<<<2048, 256, 0, stream>>>(zlist, zcount, ent, z2t, partials, NRES_);
  zmerge_kernel<<<128, 256, 0, stream>>>(zlist, zcount, partials, resent, out, NRES_);
  mlp_kernel<<<(N + 63) / 64, 256, 0, stream>>>(feat, W1b, b1, W2b, b2, out, N);
}